// Round 3
// baseline (537.844 us; speedup 1.0000x reference)
//
#include <hip/hip_runtime.h>
#include <hip/hip_bf16.h>
#include <stdint.h>

typedef unsigned short u16;
typedef __attribute__((ext_vector_type(8))) short short8;   // 8 bf16 in 4 VGPRs (guide §3)
typedef __attribute__((ext_vector_type(4))) float f32x4;

#define BM 128
#define BN 128
#define BK 32

__device__ inline u16 f2bf(float f) {
  union { float f; uint32_t u; } x; x.f = f;
  uint32_t r = (x.u + 0x7FFFu + ((x.u >> 16) & 1u)) >> 16;
  return (u16)r;
}

__device__ inline void async_load16(const void* g, void* l) {
  __builtin_amdgcn_global_load_lds(
      (const __attribute__((address_space(1))) void*)g,
      (__attribute__((address_space(3))) void*)l, 16, 0, 0);
}

// ---------------- f32 -> bf16 elementwise (vectorized) ----------------
__global__ __launch_bounds__(256) void f32_to_bf16_k(
    const float* __restrict__ in, u16* __restrict__ out, int n4) {
  int i = blockIdx.x * 256 + threadIdx.x;
  if (i >= n4) return;
  float4 v = reinterpret_cast<const float4*>(in)[i];
  ushort4 o;
  o.x = f2bf(v.x); o.y = f2bf(v.y); o.z = f2bf(v.z); o.w = f2bf(v.w);
  reinterpret_cast<ushort4*>(out)[i] = o;
}

// ---- f32 [R][Cc] -> bf16 transposed [Cc][R]  AND bf16 non-transposed [R][Cc] ----
__global__ __launch_bounds__(256) void transpose_f32_bf16_k(
    const float* __restrict__ in, u16* __restrict__ out_t,
    u16* __restrict__ out_nt, int R, int Cc) {
  __shared__ float tile[32][33];
  int tx = threadIdx.x & 31;
  int ty = threadIdx.x >> 5;  // 0..7
  int c = blockIdx.x * 32 + tx;
#pragma unroll
  for (int j = 0; j < 4; j++) {
    int r = blockIdx.y * 32 + ty + j * 8;
    float v = in[(size_t)r * Cc + c];
    tile[ty + j * 8][tx] = v;
    out_nt[(size_t)r * Cc + c] = f2bf(v);
  }
  __syncthreads();
  int rr = blockIdx.y * 32 + tx;
#pragma unroll
  for (int j = 0; j < 4; j++) {
    int cc = blockIdx.x * 32 + ty + j * 8;
    out_t[(size_t)cc * R + rr] = f2bf(tile[tx][ty + j * 8]);
  }
}

// ---- row softmax: fp32 scores [rows][C] -> bf16 probs packed into the ----
// ---- second half of each row's own fp32 region (in-place, race-free)  ----
// P base = (u16*)S + C; probs row r lives at u16 index r*2C + C + c.
__global__ __launch_bounds__(256) void softmax_rows_k(
    const float* __restrict__ S, u16* __restrict__ P, int C) {
  const float4* src = reinterpret_cast<const float4*>(S + (size_t)blockIdx.x * C);
  ushort4* dst = reinterpret_cast<ushort4*>(P + (size_t)blockIdx.x * 2 * C);
  const int t = threadIdx.x;
  float4 v[4];
  float mx = -3.4e38f;
#pragma unroll
  for (int j = 0; j < 4; j++) {
    v[j] = src[j * 256 + t];
    mx = fmaxf(mx, fmaxf(fmaxf(v[j].x, v[j].y), fmaxf(v[j].z, v[j].w)));
  }
#pragma unroll
  for (int i = 1; i < 64; i <<= 1) mx = fmaxf(mx, __shfl_xor(mx, i));
  __shared__ float red[8];
  if ((t & 63) == 0) red[t >> 6] = mx;
  __syncthreads();
  mx = fmaxf(fmaxf(red[0], red[1]), fmaxf(red[2], red[3]));
  float e[16];
  float sum = 0.f;
#pragma unroll
  for (int j = 0; j < 4; j++) {
    e[j * 4 + 0] = __expf(v[j].x - mx);
    e[j * 4 + 1] = __expf(v[j].y - mx);
    e[j * 4 + 2] = __expf(v[j].z - mx);
    e[j * 4 + 3] = __expf(v[j].w - mx);
    sum += (e[j * 4 + 0] + e[j * 4 + 1]) + (e[j * 4 + 2] + e[j * 4 + 3]);
  }
#pragma unroll
  for (int i = 1; i < 64; i <<= 1) sum += __shfl_xor(sum, i);
  if ((t & 63) == 0) red[4 + (t >> 6)] = sum;
  __syncthreads();
  sum = (red[4] + red[5]) + (red[6] + red[7]);
  float inv = 1.0f / sum;
#pragma unroll
  for (int j = 0; j < 4; j++) {
    ushort4 o;
    o.x = f2bf(e[j * 4 + 0] * inv);
    o.y = f2bf(e[j * 4 + 1] * inv);
    o.z = f2bf(e[j * 4 + 2] * inv);
    o.w = f2bf(e[j * 4 + 3] * inv);
    dst[j * 256 + t] = o;
  }
}

// ---------------- bf16 GEMM, B^T layout: C[M][N] = A[M][K] * B[N][K]^T ----------------
// A rows have stride lda (elements); B rows have stride K.
// EPI 0: outF = acc                     (scores, fp32)
// EPI 1: outBF = bf16(acc + aux[m][n])  (residual add, bf16 out)
// EPI 2: outF = leakyrelu(acc + aux[n]) (bias + LeakyReLU, fp32 out)
template <int EPI>
__global__ __launch_bounds__(256) void gemm_bt_k(
    const u16* __restrict__ A, const u16* __restrict__ B,
    int M, int N, int K, int lda,
    float* __restrict__ outF, u16* __restrict__ outBF,
    const float* __restrict__ aux) {
  __shared__ u16 lds_a[BM * BK];
  __shared__ u16 lds_b[BN * BK];

  const int tid = threadIdx.x;
  const int mBase = blockIdx.y * BM;
  const int nBase = blockIdx.x * BN;

  const int l = tid & 63;
  const int w = tid >> 6;        // wave 0..3
  const int wr = w >> 1;         // wave row 0..1 (64-row half)
  const int wc = w & 1;          // wave col 0..1
  const int fr = l & 15;         // fragment row/col within 16
  const int kb = (l >> 4) * 8;   // k element offset for this lane

  f32x4 acc[4][4];
#pragma unroll
  for (int m = 0; m < 4; m++)
#pragma unroll
    for (int n = 0; n < 4; n++) acc[m][n] = (f32x4)0.f;

  for (int k0 = 0; k0 < K; k0 += BK) {
    // stage A and B tiles: each 128 rows x 32 k bf16 = 8 KB, linear LDS.
    // chunk id c = q*256+tid is linear in lane with 16B stride -> matches
    // global_load_lds's wave-uniform-base + lane*16 write pattern.
#pragma unroll
    for (int q = 0; q < 2; q++) {
      int c = q * 256 + tid;      // 16B chunk id, 512 chunks per tile
      int row = c >> 2;           // 4 chunks (64B) per row
      int kc = (c & 3) * 8;       // element offset within row
      async_load16(&A[(size_t)(mBase + row) * lda + k0 + kc], &lds_a[c * 8]);
      async_load16(&B[(size_t)(nBase + row) * K + k0 + kc], &lds_b[c * 8]);
    }
    __syncthreads();

    short8 af[4], bfr[4];
#pragma unroll
    for (int m = 0; m < 4; m++)
      af[m] = *reinterpret_cast<const short8*>(&lds_a[(wr * 64 + m * 16 + fr) * BK + kb]);
#pragma unroll
    for (int n = 0; n < 4; n++)
      bfr[n] = *reinterpret_cast<const short8*>(&lds_b[(wc * 64 + n * 16 + fr) * BK + kb]);

#pragma unroll
    for (int m = 0; m < 4; m++)
#pragma unroll
      for (int n = 0; n < 4; n++)
        acc[m][n] = __builtin_amdgcn_mfma_f32_16x16x32_bf16(af[m], bfr[n], acc[m][n], 0, 0, 0);
    __syncthreads();
  }

  // epilogue: D frag (m,n), reg r -> row = wr*64+m*16+(l>>4)*4+r, col = wc*64+n*16+(l&15)
#pragma unroll
  for (int m = 0; m < 4; m++) {
#pragma unroll
    for (int n = 0; n < 4; n++) {
      int col = nBase + wc * 64 + n * 16 + fr;
#pragma unroll
      for (int r = 0; r < 4; r++) {
        int row = mBase + wr * 64 + m * 16 + (l >> 4) * 4 + r;
        size_t o = (size_t)row * N + col;
        float v = acc[m][n][r];
        if (EPI == 0) {
          outF[o] = v;
        } else if (EPI == 1) {
          outBF[o] = f2bf(v + aux[o]);
        } else {
          v += aux[col];
          outF[o] = (v >= 0.f) ? v : 0.01f * v;
        }
      }
    }
  }
}

extern "C" void kernel_launch(void* const* d_in, const int* in_sizes, int n_in,
                              void* d_out, int out_size, void* d_ws, size_t ws_size,
                              hipStream_t stream) {
  const float* x = (const float*)d_in[0];     // [Mrows, D]
  const float* E = (const float*)d_in[1];     // [C, D]
  const float* W = (const float*)d_in[2];     // [C, D]
  const float* bias = (const float*)d_in[3];  // [C]

  const int C = in_sizes[3];              // 4096
  const int D = in_sizes[1] / C;          // 1024
  const int Mrows = in_sizes[0] / D;      // 8192

  char* p = (char*)d_ws;
  u16* xbf = (u16*)p;   p += (size_t)Mrows * D * 2;   // 16 MB
  u16* Ebf = (u16*)p;   p += (size_t)C * D * 2;       // 8 MB
  u16* Etbf = (u16*)p;  p += (size_t)C * D * 2;       // 8 MB (E^T: [D][C])
  u16* Wbf = (u16*)p;   p += (size_t)C * D * 2;       // 8 MB
  u16* x2bf = (u16*)p;  p += (size_t)Mrows * D * 2;   // 16 MB
  float* scores = (float*)p;                          // 128 MB (probs packed inside)
  // probs row r: u16 elements [r*2C + C, r*2C + 2C) of the scores region
  u16* probs = (u16*)scores + C;   // use with lda = 2*C

  // 1) conversions (E's bf16 copy is fused into the transpose kernel)
  {
    int n4 = Mrows * D / 4;
    f32_to_bf16_k<<<(n4 + 255) / 256, 256, 0, stream>>>(x, xbf, n4);
  }
  {
    int n4 = C * D / 4;
    f32_to_bf16_k<<<(n4 + 255) / 256, 256, 0, stream>>>(W, Wbf, n4);
  }
  transpose_f32_bf16_k<<<dim3(D / 32, C / 32), 256, 0, stream>>>(E, Etbf, Ebf, C, D);

  // 2) scores = x @ E^T   [Mrows, C] fp32
  gemm_bt_k<0><<<dim3(C / BN, Mrows / BM), 256, 0, stream>>>(
      xbf, Ebf, Mrows, C, D, D, scores, nullptr, nullptr);

  // 3) probs = softmax(scores) -> bf16, packed in-place
  softmax_rows_k<<<Mrows, 256, 0, stream>>>(scores, probs, C);

  // 4) x2 = x + probs @ E   [Mrows, D] bf16   (A = probs, lda = 2C)
  gemm_bt_k<1><<<dim3(D / BN, Mrows / BM), 256, 0, stream>>>(
      probs, Etbf, Mrows, D, C, 2 * C, nullptr, x2bf, x);

  // 5) out = leakyrelu(x2 @ W^T + b)  [Mrows, C] fp32
  gemm_bt_k<2><<<dim3(C / BN, Mrows / BM), 256, 0, stream>>>(
      x2bf, Wbf, Mrows, C, D, D, (float*)d_out, nullptr, bias);
}

// Round 4
// 486.538 us; speedup vs baseline: 1.1054x; 1.1054x over previous
//
#include <hip/hip_runtime.h>
#include <hip/hip_bf16.h>
#include <stdint.h>

typedef unsigned short u16;
typedef __attribute__((ext_vector_type(8))) short short8;   // 8 bf16 (4 VGPRs)
typedef __attribute__((ext_vector_type(4))) float f32x4;

#define BK 32

__device__ inline u16 f2bf(float f) {
  union { float f; uint32_t u; } x; x.f = f;
  uint32_t r = (x.u + 0x7FFFu + ((x.u >> 16) & 1u)) >> 16;
  return (u16)r;
}

__device__ inline void async_load16(const void* g, void* l) {
  __builtin_amdgcn_global_load_lds(
      (const __attribute__((address_space(1))) void*)g,
      (__attribute__((address_space(3))) void*)l, 16, 0, 0);
}

// XCD-aware bijective block remap; requires gridDim.x*gridDim.y % 8 == 0.
__device__ inline void xcd_remap(int& bx, int& by) {
  int gx = gridDim.x;
  int nwg = gx * gridDim.y;
  int flat = by * gx + bx;
  int swz = (flat & 7) * (nwg >> 3) + (flat >> 3);
  bx = swz % gx;
  by = swz / gx;
}

// ---------------- f32 -> bf16 elementwise (vectorized) ----------------
__global__ __launch_bounds__(256) void f32_to_bf16_k(
    const float* __restrict__ in, u16* __restrict__ out, int n4) {
  int i = blockIdx.x * 256 + threadIdx.x;
  if (i >= n4) return;
  float4 v = reinterpret_cast<const float4*>(in)[i];
  ushort4 o;
  o.x = f2bf(v.x); o.y = f2bf(v.y); o.z = f2bf(v.z); o.w = f2bf(v.w);
  reinterpret_cast<ushort4*>(out)[i] = o;
}

// ---- f32 [R][Cc] -> bf16 transposed [Cc][R]  AND bf16 non-transposed [R][Cc] ----
__global__ __launch_bounds__(256) void transpose_f32_bf16_k(
    const float* __restrict__ in, u16* __restrict__ out_t,
    u16* __restrict__ out_nt, int R, int Cc) {
  __shared__ float tile[32][33];
  int tx = threadIdx.x & 31;
  int ty = threadIdx.x >> 5;  // 0..7
  int c = blockIdx.x * 32 + tx;
#pragma unroll
  for (int j = 0; j < 4; j++) {
    int r = blockIdx.y * 32 + ty + j * 8;
    float v = in[(size_t)r * Cc + c];
    tile[ty + j * 8][tx] = v;
    out_nt[(size_t)r * Cc + c] = f2bf(v);
  }
  __syncthreads();
  int rr = blockIdx.y * 32 + tx;
#pragma unroll
  for (int j = 0; j < 4; j++) {
    int cc = blockIdx.x * 32 + ty + j * 8;
    out_t[(size_t)cc * R + rr] = f2bf(tile[tx][ty + j * 8]);
  }
}

// ---- row softmax: fp32 scores [rows][C] -> bf16 probs packed into the ----
// ---- second half of each row's own fp32 region (in-place, race-free)  ----
// P base = (u16*)S + C; probs row r lives at u16 index r*2C + C + c.
__global__ __launch_bounds__(256) void softmax_rows_k(
    const float* __restrict__ S, u16* __restrict__ P, int C) {
  const float4* src = reinterpret_cast<const float4*>(S + (size_t)blockIdx.x * C);
  ushort4* dst = reinterpret_cast<ushort4*>(P + (size_t)blockIdx.x * 2 * C);
  const int t = threadIdx.x;
  float4 v[4];
  float mx = -3.4e38f;
#pragma unroll
  for (int j = 0; j < 4; j++) {
    v[j] = src[j * 256 + t];
    mx = fmaxf(mx, fmaxf(fmaxf(v[j].x, v[j].y), fmaxf(v[j].z, v[j].w)));
  }
#pragma unroll
  for (int i = 1; i < 64; i <<= 1) mx = fmaxf(mx, __shfl_xor(mx, i));
  __shared__ float red[8];
  if ((t & 63) == 0) red[t >> 6] = mx;
  __syncthreads();
  mx = fmaxf(fmaxf(red[0], red[1]), fmaxf(red[2], red[3]));
  float e[16];
  float sum = 0.f;
#pragma unroll
  for (int j = 0; j < 4; j++) {
    e[j * 4 + 0] = __expf(v[j].x - mx);
    e[j * 4 + 1] = __expf(v[j].y - mx);
    e[j * 4 + 2] = __expf(v[j].z - mx);
    e[j * 4 + 3] = __expf(v[j].w - mx);
    sum += (e[j * 4 + 0] + e[j * 4 + 1]) + (e[j * 4 + 2] + e[j * 4 + 3]);
  }
#pragma unroll
  for (int i = 1; i < 64; i <<= 1) sum += __shfl_xor(sum, i);
  if ((t & 63) == 0) red[4 + (t >> 6)] = sum;
  __syncthreads();
  sum = (red[4] + red[5]) + (red[6] + red[7]);
  float inv = 1.0f / sum;
#pragma unroll
  for (int j = 0; j < 4; j++) {
    ushort4 o;
    o.x = f2bf(e[j * 4 + 0] * inv);
    o.y = f2bf(e[j * 4 + 1] * inv);
    o.z = f2bf(e[j * 4 + 2] * inv);
    o.w = f2bf(e[j * 4 + 3] * inv);
    dst[j * 256 + t] = o;
  }
}

// ============ 256x256 tile bf16 GEMM (8 waves), B^T: C = A[M,K] * B[N,K]^T ============
// dbuf 2-phase loop; source-pre-swizzled staging (chunk ^= (row>>1)&3) with
// matching XOR on ds_read -> 2-way (free) bank aliasing instead of 8-way.
// EPI 0: outF = acc; EPI 2: outF = leakyrelu(acc + aux[col])
template <int EPI>
__global__ __launch_bounds__(512, 2) void gemm_bt256_k(
    const u16* __restrict__ A, const u16* __restrict__ B,
    int M, int N, int K, int lda,
    float* __restrict__ outF, u16* __restrict__ outBF,
    const float* __restrict__ aux) {
  __shared__ u16 sA[2][256 * BK];   // 2 x 16 KB
  __shared__ u16 sB[2][256 * BK];   // 2 x 16 KB

  int bx = blockIdx.x, by = blockIdx.y;
  xcd_remap(bx, by);
  const int mBase = by * 256;
  const int nBase = bx * 256;

  const int tid = threadIdx.x;           // 0..511
  const int l = tid & 63;
  const int w = tid >> 6;                // 0..7
  const int wr = w >> 2;                 // 0..1  (128-row half)
  const int wc = w & 3;                  // 0..3  (64-col quarter)
  const int fr = l & 15;
  const int kc4 = l >> 4;                // k-chunk 0..3

  f32x4 acc[8][4];
#pragma unroll
  for (int m = 0; m < 8; m++)
#pragma unroll
    for (int n = 0; n < 4; n++) acc[m][n] = (f32x4)0.f;

  auto stage = [&](int buf, int k0) {
#pragma unroll
    for (int q = 0; q < 2; q++) {
      int c = q * 512 + tid;             // 16B chunk id, 1024 per tile
      int row = c >> 2;
      int cs = c & 3;
      int kc = ((cs ^ ((row >> 1) & 3)) << 3);   // source pre-swizzle
      async_load16(&A[(size_t)(mBase + row) * lda + k0 + kc], &sA[buf][c * 8]);
      async_load16(&B[(size_t)(nBase + row) * K + k0 + kc], &sB[buf][c * 8]);
    }
  };

  const int nt = K / BK;
  stage(0, 0);
  __syncthreads();     // drains vmcnt(0): tile 0 resident
  int cur = 0;
  for (int t = 0; t < nt; ++t) {
    if (t + 1 < nt) stage(cur ^ 1, (t + 1) * BK);

    short8 af[8], bf[4];
#pragma unroll
    for (int m = 0; m < 8; m++) {
      int row = wr * 128 + m * 16 + fr;
      af[m] = *reinterpret_cast<const short8*>(
          &sA[cur][row * BK + ((kc4 ^ ((row >> 1) & 3)) << 3)]);
    }
#pragma unroll
    for (int n = 0; n < 4; n++) {
      int row = wc * 64 + n * 16 + fr;
      bf[n] = *reinterpret_cast<const short8*>(
          &sB[cur][row * BK + ((kc4 ^ ((row >> 1) & 3)) << 3)]);
    }
#pragma unroll
    for (int m = 0; m < 8; m++)
#pragma unroll
      for (int n = 0; n < 4; n++)
        acc[m][n] = __builtin_amdgcn_mfma_f32_16x16x32_bf16(af[m], bf[n], acc[m][n], 0, 0, 0);

    __syncthreads();   // drains vmcnt(0): tile t+1 resident; all reads of cur done
    cur ^= 1;
  }

  // epilogue: row = mBase + wr*128 + m*16 + (l>>4)*4 + r, col = nBase + wc*64 + n*16 + fr
#pragma unroll
  for (int m = 0; m < 8; m++) {
#pragma unroll
    for (int n = 0; n < 4; n++) {
      int col = nBase + wc * 64 + n * 16 + fr;
#pragma unroll
      for (int r = 0; r < 4; r++) {
        int row = mBase + wr * 128 + m * 16 + (l >> 4) * 4 + r;
        size_t o = (size_t)row * N + col;
        float v = acc[m][n][r];
        if (EPI == 0) {
          outF[o] = v;
        } else if (EPI == 1) {
          outBF[o] = f2bf(v + aux[o]);
        } else {
          v += aux[col];
          outF[o] = (v >= 0.f) ? v : 0.01f * v;
        }
      }
    }
  }
}

// ============ 128x128 tile bf16 GEMM (4 waves), B^T layout ============
// Same dbuf + swizzle treatment. Used for the K=4096, N=1024 GEMM2.
template <int EPI>
__global__ __launch_bounds__(256, 3) void gemm_bt_k(
    const u16* __restrict__ A, const u16* __restrict__ B,
    int M, int N, int K, int lda,
    float* __restrict__ outF, u16* __restrict__ outBF,
    const float* __restrict__ aux) {
  __shared__ u16 sA[2][128 * BK];   // 2 x 8 KB
  __shared__ u16 sB[2][128 * BK];   // 2 x 8 KB

  int bx = blockIdx.x, by = blockIdx.y;
  xcd_remap(bx, by);
  const int mBase = by * 128;
  const int nBase = bx * 128;

  const int tid = threadIdx.x;
  const int l = tid & 63;
  const int w = tid >> 6;        // 0..3
  const int wr = w >> 1;
  const int wc = w & 1;
  const int fr = l & 15;
  const int kc4 = l >> 4;

  f32x4 acc[4][4];
#pragma unroll
  for (int m = 0; m < 4; m++)
#pragma unroll
    for (int n = 0; n < 4; n++) acc[m][n] = (f32x4)0.f;

  auto stage = [&](int buf, int k0) {
#pragma unroll
    for (int q = 0; q < 2; q++) {
      int c = q * 256 + tid;     // 512 chunks per tile
      int row = c >> 2;
      int cs = c & 3;
      int kc = ((cs ^ ((row >> 1) & 3)) << 3);
      async_load16(&A[(size_t)(mBase + row) * lda + k0 + kc], &sA[buf][c * 8]);
      async_load16(&B[(size_t)(nBase + row) * K + k0 + kc], &sB[buf][c * 8]);
    }
  };

  const int nt = K / BK;
  stage(0, 0);
  __syncthreads();
  int cur = 0;
  for (int t = 0; t < nt; ++t) {
    if (t + 1 < nt) stage(cur ^ 1, (t + 1) * BK);

    short8 af[4], bf[4];
#pragma unroll
    for (int m = 0; m < 4; m++) {
      int row = wr * 64 + m * 16 + fr;
      af[m] = *reinterpret_cast<const short8*>(
          &sA[cur][row * BK + ((kc4 ^ ((row >> 1) & 3)) << 3)]);
    }
#pragma unroll
    for (int n = 0; n < 4; n++) {
      int row = wc * 64 + n * 16 + fr;
      bf[n] = *reinterpret_cast<const short8*>(
          &sB[cur][row * BK + ((kc4 ^ ((row >> 1) & 3)) << 3)]);
    }
#pragma unroll
    for (int m = 0; m < 4; m++)
#pragma unroll
      for (int n = 0; n < 4; n++)
        acc[m][n] = __builtin_amdgcn_mfma_f32_16x16x32_bf16(af[m], bf[n], acc[m][n], 0, 0, 0);

    __syncthreads();
    cur ^= 1;
  }

#pragma unroll
  for (int m = 0; m < 4; m++) {
#pragma unroll
    for (int n = 0; n < 4; n++) {
      int col = nBase + wc * 64 + n * 16 + fr;
#pragma unroll
      for (int r = 0; r < 4; r++) {
        int row = mBase + wr * 64 + m * 16 + (l >> 4) * 4 + r;
        size_t o = (size_t)row * N + col;
        float v = acc[m][n][r];
        if (EPI == 0) {
          outF[o] = v;
        } else if (EPI == 1) {
          outBF[o] = f2bf(v + aux[o]);
        } else {
          v += aux[col];
          outF[o] = (v >= 0.f) ? v : 0.01f * v;
        }
      }
    }
  }
}

extern "C" void kernel_launch(void* const* d_in, const int* in_sizes, int n_in,
                              void* d_out, int out_size, void* d_ws, size_t ws_size,
                              hipStream_t stream) {
  const float* x = (const float*)d_in[0];     // [Mrows, D]
  const float* E = (const float*)d_in[1];     // [C, D]
  const float* W = (const float*)d_in[2];     // [C, D]
  const float* bias = (const float*)d_in[3];  // [C]

  const int C = in_sizes[3];              // 4096
  const int D = in_sizes[1] / C;          // 1024
  const int Mrows = in_sizes[0] / D;      // 8192

  char* p = (char*)d_ws;
  u16* xbf = (u16*)p;   p += (size_t)Mrows * D * 2;   // 16 MB
  u16* Ebf = (u16*)p;   p += (size_t)C * D * 2;       // 8 MB
  u16* Etbf = (u16*)p;  p += (size_t)C * D * 2;       // 8 MB (E^T: [D][C])
  u16* Wbf = (u16*)p;   p += (size_t)C * D * 2;       // 8 MB
  u16* x2bf = (u16*)p;  p += (size_t)Mrows * D * 2;   // 16 MB
  float* scores = (float*)p;                          // 128 MB (probs packed inside)
  u16* probs = (u16*)scores + C;   // probs row r at u16 r*2C + C; lda = 2*C

  // 1) conversions (E's bf16 copy fused into the transpose kernel)
  {
    int n4 = Mrows * D / 4;
    f32_to_bf16_k<<<(n4 + 255) / 256, 256, 0, stream>>>(x, xbf, n4);
  }
  {
    int n4 = C * D / 4;
    f32_to_bf16_k<<<(n4 + 255) / 256, 256, 0, stream>>>(W, Wbf, n4);
  }
  transpose_f32_bf16_k<<<dim3(D / 32, C / 32), 256, 0, stream>>>(E, Etbf, Ebf, C, D);

  // 2) scores = x @ E^T   [Mrows, C] fp32   (256^2 tiles: 16x32 = 512 blocks)
  gemm_bt256_k<0><<<dim3(C / 256, Mrows / 256), 512, 0, stream>>>(
      xbf, Ebf, Mrows, C, D, D, scores, nullptr, nullptr);

  // 3) probs = softmax(scores) -> bf16, packed in-place
  softmax_rows_k<<<Mrows, 256, 0, stream>>>(scores, probs, C);

  // 4) x2 = x + probs @ E   [Mrows, D] bf16   (A = probs, lda = 2C; 8x64 = 512 blocks)
  gemm_bt_k<1><<<dim3(D / 128, Mrows / 128), 256, 0, stream>>>(
      probs, Etbf, Mrows, D, C, 2 * C, nullptr, x2bf, x);

  // 5) out = leakyrelu(x2 @ W^T + b)  [Mrows, C] fp32  (256^2 tiles)
  gemm_bt256_k<2><<<dim3(C / 256, Mrows / 256), 512, 0, stream>>>(
      x2bf, Wbf, Mrows, C, D, D, (float*)d_out, nullptr, bias);
}

// Round 5
// 475.004 us; speedup vs baseline: 1.1323x; 1.0243x over previous
//
#include <hip/hip_runtime.h>
#include <hip/hip_bf16.h>
#include <stdint.h>

typedef unsigned short u16;
typedef __attribute__((ext_vector_type(8))) short short8;   // 8 bf16 (4 VGPRs)
typedef __attribute__((ext_vector_type(4))) float f32x4;

#define BK 32

__device__ inline u16 f2bf(float f) {
  union { float f; uint32_t u; } x; x.f = f;
  uint32_t r = (x.u + 0x7FFFu + ((x.u >> 16) & 1u)) >> 16;
  return (u16)r;
}

__device__ inline void async_load16(const void* g, void* l) {
  __builtin_amdgcn_global_load_lds(
      (const __attribute__((address_space(1))) void*)g,
      (__attribute__((address_space(3))) void*)l, 16, 0, 0);
}

// XCD-aware bijective block remap; requires gridDim.x*gridDim.y % 8 == 0.
__device__ inline void xcd_remap(int& bx, int& by) {
  int gx = gridDim.x;
  int nwg = gx * gridDim.y;
  int flat = by * gx + bx;
  int swz = (flat & 7) * (nwg >> 3) + (flat >> 3);
  bx = swz % gx;
  by = swz / gx;
}

// ---------------- f32 -> bf16 elementwise (vectorized) ----------------
__global__ __launch_bounds__(256) void f32_to_bf16_k(
    const float* __restrict__ in, u16* __restrict__ out, int n4) {
  int i = blockIdx.x * 256 + threadIdx.x;
  if (i >= n4) return;
  float4 v = reinterpret_cast<const float4*>(in)[i];
  ushort4 o;
  o.x = f2bf(v.x); o.y = f2bf(v.y); o.z = f2bf(v.z); o.w = f2bf(v.w);
  reinterpret_cast<ushort4*>(out)[i] = o;
}

// ---- f32 [R][Cc] -> bf16 transposed [Cc][R]  AND bf16 non-transposed [R][Cc] ----
__global__ __launch_bounds__(256) void transpose_f32_bf16_k(
    const float* __restrict__ in, u16* __restrict__ out_t,
    u16* __restrict__ out_nt, int R, int Cc) {
  __shared__ float tile[32][33];
  int tx = threadIdx.x & 31;
  int ty = threadIdx.x >> 5;  // 0..7
  int c = blockIdx.x * 32 + tx;
#pragma unroll
  for (int j = 0; j < 4; j++) {
    int r = blockIdx.y * 32 + ty + j * 8;
    float v = in[(size_t)r * Cc + c];
    tile[ty + j * 8][tx] = v;
    out_nt[(size_t)r * Cc + c] = f2bf(v);
  }
  __syncthreads();
  int rr = blockIdx.y * 32 + tx;
#pragma unroll
  for (int j = 0; j < 4; j++) {
    int cc = blockIdx.x * 32 + ty + j * 8;
    out_t[(size_t)cc * R + rr] = f2bf(tile[tx][ty + j * 8]);
  }
}

// ---- row softmax: fp32 scores [rows][C] -> bf16 probs packed into the ----
// ---- second half of each row's own fp32 region (in-place, race-free)  ----
// P base = (u16*)S + C; probs row r lives at u16 index r*2C + C + c.
__global__ __launch_bounds__(256) void softmax_rows_k(
    const float* __restrict__ S, u16* __restrict__ P, int C) {
  const float4* src = reinterpret_cast<const float4*>(S + (size_t)blockIdx.x * C);
  ushort4* dst = reinterpret_cast<ushort4*>(P + (size_t)blockIdx.x * 2 * C);
  const int t = threadIdx.x;
  float4 v[4];
  float mx = -3.4e38f;
#pragma unroll
  for (int j = 0; j < 4; j++) {
    v[j] = src[j * 256 + t];
    mx = fmaxf(mx, fmaxf(fmaxf(v[j].x, v[j].y), fmaxf(v[j].z, v[j].w)));
  }
#pragma unroll
  for (int i = 1; i < 64; i <<= 1) mx = fmaxf(mx, __shfl_xor(mx, i));
  __shared__ float red[8];
  if ((t & 63) == 0) red[t >> 6] = mx;
  __syncthreads();
  mx = fmaxf(fmaxf(red[0], red[1]), fmaxf(red[2], red[3]));
  float e[16];
  float sum = 0.f;
#pragma unroll
  for (int j = 0; j < 4; j++) {
    e[j * 4 + 0] = __expf(v[j].x - mx);
    e[j * 4 + 1] = __expf(v[j].y - mx);
    e[j * 4 + 2] = __expf(v[j].z - mx);
    e[j * 4 + 3] = __expf(v[j].w - mx);
    sum += (e[j * 4 + 0] + e[j * 4 + 1]) + (e[j * 4 + 2] + e[j * 4 + 3]);
  }
#pragma unroll
  for (int i = 1; i < 64; i <<= 1) sum += __shfl_xor(sum, i);
  if ((t & 63) == 0) red[4 + (t >> 6)] = sum;
  __syncthreads();
  sum = (red[4] + red[5]) + (red[6] + red[7]);
  float inv = 1.0f / sum;
#pragma unroll
  for (int j = 0; j < 4; j++) {
    ushort4 o;
    o.x = f2bf(e[j * 4 + 0] * inv);
    o.y = f2bf(e[j * 4 + 1] * inv);
    o.z = f2bf(e[j * 4 + 2] * inv);
    o.w = f2bf(e[j * 4 + 3] * inv);
    dst[j * 256 + t] = o;
  }
}

// ============ 256x256 tile bf16 GEMM (8 waves), B^T: C = A[M,K] * B[N,K]^T ============
// 4-slot staging ring + counted vmcnt + raw barriers (T4): loads stay in flight
// across barriers; only counted waits in the main loop. Source-pre-swizzled
// staging (chunk ^= (row>>1)&3) with matching XOR on ds_read (0 bank conflicts).
template <int EPI>
__global__ __launch_bounds__(512, 2) void gemm_bt256_k(
    const u16* __restrict__ A, const u16* __restrict__ B,
    int M, int N, int K, int lda,
    float* __restrict__ outF, u16* __restrict__ outBF,
    const float* __restrict__ aux) {
  __shared__ u16 sA[4][256 * BK];   // 4 x 16 KB
  __shared__ u16 sB[4][256 * BK];   // 4 x 16 KB   (128 KB total -> 1 block/CU)

  int bx = blockIdx.x, by = blockIdx.y;
  xcd_remap(bx, by);
  const int mBase = by * 256;
  const int nBase = bx * 256;

  const int tid = threadIdx.x;           // 0..511
  const int l = tid & 63;
  const int w = tid >> 6;                // 0..7
  const int wr = w >> 2;                 // 0..1  (128-row half)
  const int wc = w & 3;                  // 0..3  (64-col quarter)
  const int fr = l & 15;
  const int kc4 = l >> 4;                // k-chunk 0..3

  f32x4 acc[8][4];
#pragma unroll
  for (int m = 0; m < 8; m++)
#pragma unroll
    for (int n = 0; n < 4; n++) acc[m][n] = (f32x4)0.f;

  auto stage = [&](int slot, int k0) {
#pragma unroll
    for (int q = 0; q < 2; q++) {
      int c = q * 512 + tid;             // 16B chunk id, 1024 per tile
      int row = c >> 2;
      int cs = c & 3;
      int kc = ((cs ^ ((row >> 1) & 3)) << 3);   // source pre-swizzle
      async_load16(&A[(size_t)(mBase + row) * lda + k0 + kc], &sA[slot][c * 8]);
      async_load16(&B[(size_t)(nBase + row) * K + k0 + kc], &sB[slot][c * 8]);
    }
  };

  const int nt = K / BK;                 // >= 4 for all our shapes
  stage(0, 0); stage(1, BK); stage(2, 2 * BK); stage(3, 3 * BK);

  for (int t = 0; t < nt; ++t) {
    // own stage-t loads landed (3 newer stages x 4 loads = 12 may remain)
    asm volatile("s_waitcnt vmcnt(12)" ::: "memory");
    __builtin_amdgcn_s_barrier();        // B1: everyone's stage-t landed

    const u16* sa = sA[t & 3];
    const u16* sb = sB[t & 3];
    short8 af[8], bf[4];
#pragma unroll
    for (int m = 0; m < 8; m++) {
      int row = wr * 128 + m * 16 + fr;
      af[m] = *reinterpret_cast<const short8*>(
          &sa[row * BK + ((kc4 ^ ((row >> 1) & 3)) << 3)]);
    }
#pragma unroll
    for (int n = 0; n < 4; n++) {
      int row = wc * 64 + n * 16 + fr;
      bf[n] = *reinterpret_cast<const short8*>(
          &sb[row * BK + ((kc4 ^ ((row >> 1) & 3)) << 3)]);
    }

    __builtin_amdgcn_s_setprio(1);
#pragma unroll
    for (int m = 0; m < 8; m++)
#pragma unroll
      for (int n = 0; n < 4; n++)
        acc[m][n] = __builtin_amdgcn_mfma_f32_16x16x32_bf16(af[m], bf[n], acc[m][n], 0, 0, 0);
    __builtin_amdgcn_s_setprio(0);

    // pin DS completion before the barrier: closes WAR on slot t&3
    asm volatile("s_waitcnt lgkmcnt(0)" ::: "memory");
    __builtin_amdgcn_s_barrier();        // B2: all waves done reading slot t&3
    if (t + 4 < nt) stage((t + 4) & 3, (t + 4) * BK);
  }

  // epilogue: row = mBase + wr*128 + m*16 + (l>>4)*4 + r, col = nBase + wc*64 + n*16 + fr
#pragma unroll
  for (int m = 0; m < 8; m++) {
#pragma unroll
    for (int n = 0; n < 4; n++) {
      int col = nBase + wc * 64 + n * 16 + fr;
#pragma unroll
      for (int r = 0; r < 4; r++) {
        int row = mBase + wr * 128 + m * 16 + (l >> 4) * 4 + r;
        size_t o = (size_t)row * N + col;
        float v = acc[m][n][r];
        if (EPI == 0) {
          outF[o] = v;
        } else if (EPI == 1) {
          outBF[o] = f2bf(v + aux[o]);
        } else {
          v += aux[col];
          outF[o] = (v >= 0.f) ? v : 0.01f * v;
        }
      }
    }
  }
}

// ============ 128x128 tile bf16 GEMM (4 waves), B^T layout ============
// Same 4-slot ring treatment. Used for the K=4096, N=1024 GEMM2.
template <int EPI>
__global__ __launch_bounds__(256, 2) void gemm_bt_k(
    const u16* __restrict__ A, const u16* __restrict__ B,
    int M, int N, int K, int lda,
    float* __restrict__ outF, u16* __restrict__ outBF,
    const float* __restrict__ aux) {
  __shared__ u16 sA[4][128 * BK];   // 4 x 8 KB
  __shared__ u16 sB[4][128 * BK];   // 4 x 8 KB   (64 KB -> 2 blocks/CU)

  int bx = blockIdx.x, by = blockIdx.y;
  xcd_remap(bx, by);
  const int mBase = by * 128;
  const int nBase = bx * 128;

  const int tid = threadIdx.x;
  const int l = tid & 63;
  const int w = tid >> 6;        // 0..3
  const int wr = w >> 1;
  const int wc = w & 1;
  const int fr = l & 15;
  const int kc4 = l >> 4;

  f32x4 acc[4][4];
#pragma unroll
  for (int m = 0; m < 4; m++)
#pragma unroll
    for (int n = 0; n < 4; n++) acc[m][n] = (f32x4)0.f;

  auto stage = [&](int slot, int k0) {
#pragma unroll
    for (int q = 0; q < 2; q++) {
      int c = q * 256 + tid;     // 512 chunks per tile
      int row = c >> 2;
      int cs = c & 3;
      int kc = ((cs ^ ((row >> 1) & 3)) << 3);
      async_load16(&A[(size_t)(mBase + row) * lda + k0 + kc], &sA[slot][c * 8]);
      async_load16(&B[(size_t)(nBase + row) * K + k0 + kc], &sB[slot][c * 8]);
    }
  };

  const int nt = K / BK;
  stage(0, 0); stage(1, BK); stage(2, 2 * BK); stage(3, 3 * BK);

  for (int t = 0; t < nt; ++t) {
    asm volatile("s_waitcnt vmcnt(12)" ::: "memory");
    __builtin_amdgcn_s_barrier();        // B1

    const u16* sa = sA[t & 3];
    const u16* sb = sB[t & 3];
    short8 af[4], bf[4];
#pragma unroll
    for (int m = 0; m < 4; m++) {
      int row = wr * 64 + m * 16 + fr;
      af[m] = *reinterpret_cast<const short8*>(
          &sa[row * BK + ((kc4 ^ ((row >> 1) & 3)) << 3)]);
    }
#pragma unroll
    for (int n = 0; n < 4; n++) {
      int row = wc * 64 + n * 16 + fr;
      bf[n] = *reinterpret_cast<const short8*>(
          &sb[row * BK + ((kc4 ^ ((row >> 1) & 3)) << 3)]);
    }

    __builtin_amdgcn_s_setprio(1);
#pragma unroll
    for (int m = 0; m < 4; m++)
#pragma unroll
      for (int n = 0; n < 4; n++)
        acc[m][n] = __builtin_amdgcn_mfma_f32_16x16x32_bf16(af[m], bf[n], acc[m][n], 0, 0, 0);
    __builtin_amdgcn_s_setprio(0);

    asm volatile("s_waitcnt lgkmcnt(0)" ::: "memory");
    __builtin_amdgcn_s_barrier();        // B2
    if (t + 4 < nt) stage((t + 4) & 3, (t + 4) * BK);
  }

#pragma unroll
  for (int m = 0; m < 4; m++) {
#pragma unroll
    for (int n = 0; n < 4; n++) {
      int col = nBase + wc * 64 + n * 16 + fr;
#pragma unroll
      for (int r = 0; r < 4; r++) {
        int row = mBase + wr * 64 + m * 16 + (l >> 4) * 4 + r;
        size_t o = (size_t)row * N + col;
        float v = acc[m][n][r];
        if (EPI == 0) {
          outF[o] = v;
        } else if (EPI == 1) {
          outBF[o] = f2bf(v + aux[o]);
        } else {
          v += aux[col];
          outF[o] = (v >= 0.f) ? v : 0.01f * v;
        }
      }
    }
  }
}

extern "C" void kernel_launch(void* const* d_in, const int* in_sizes, int n_in,
                              void* d_out, int out_size, void* d_ws, size_t ws_size,
                              hipStream_t stream) {
  const float* x = (const float*)d_in[0];     // [Mrows, D]
  const float* E = (const float*)d_in[1];     // [C, D]
  const float* W = (const float*)d_in[2];     // [C, D]
  const float* bias = (const float*)d_in[3];  // [C]

  const int C = in_sizes[3];              // 4096
  const int D = in_sizes[1] / C;          // 1024
  const int Mrows = in_sizes[0] / D;      // 8192

  char* p = (char*)d_ws;
  u16* xbf = (u16*)p;   p += (size_t)Mrows * D * 2;   // 16 MB
  u16* Ebf = (u16*)p;   p += (size_t)C * D * 2;       // 8 MB
  u16* Etbf = (u16*)p;  p += (size_t)C * D * 2;       // 8 MB (E^T: [D][C])
  u16* Wbf = (u16*)p;   p += (size_t)C * D * 2;       // 8 MB
  u16* x2bf = (u16*)p;  p += (size_t)Mrows * D * 2;   // 16 MB
  float* scores = (float*)p;                          // 128 MB (probs packed inside)
  u16* probs = (u16*)scores + C;   // probs row r at u16 r*2C + C; lda = 2*C

  // 1) conversions (E's bf16 copy fused into the transpose kernel)
  {
    int n4 = Mrows * D / 4;
    f32_to_bf16_k<<<(n4 + 255) / 256, 256, 0, stream>>>(x, xbf, n4);
  }
  {
    int n4 = C * D / 4;
    f32_to_bf16_k<<<(n4 + 255) / 256, 256, 0, stream>>>(W, Wbf, n4);
  }
  transpose_f32_bf16_k<<<dim3(D / 32, C / 32), 256, 0, stream>>>(E, Etbf, Ebf, C, D);

  // 2) scores = x @ E^T   [Mrows, C] fp32   (256^2 tiles: 16x32 = 512 blocks)
  gemm_bt256_k<0><<<dim3(C / 256, Mrows / 256), 512, 0, stream>>>(
      xbf, Ebf, Mrows, C, D, D, scores, nullptr, nullptr);

  // 3) probs = softmax(scores) -> bf16, packed in-place
  softmax_rows_k<<<Mrows, 256, 0, stream>>>(scores, probs, C);

  // 4) x2 = x + probs @ E   [Mrows, D] bf16   (A = probs, lda = 2C; 8x64 = 512 blocks)
  gemm_bt_k<1><<<dim3(D / 128, Mrows / 128), 256, 0, stream>>>(
      probs, Etbf, Mrows, D, C, 2 * C, nullptr, x2bf, x);

  // 5) out = leakyrelu(x2 @ W^T + b)  [Mrows, C] fp32  (256^2 tiles)
  gemm_bt256_k<2><<<dim3(C / 256, Mrows / 256), 512, 0, stream>>>(
      x2bf, Wbf, Mrows, C, D, D, (float*)d_out, nullptr, bias);
}

// Round 8
// 438.566 us; speedup vs baseline: 1.2264x; 1.0831x over previous
//
#include <hip/hip_runtime.h>
#include <hip/hip_bf16.h>
#include <stdint.h>

typedef unsigned short u16;
typedef __attribute__((ext_vector_type(8))) short short8;   // 8 bf16 (4 VGPRs)
typedef __attribute__((ext_vector_type(4))) float f32x4;

__device__ inline u16 f2bf(float f) {
  union { float f; uint32_t u; } x; x.f = f;
  uint32_t r = (x.u + 0x7FFFu + ((x.u >> 16) & 1u)) >> 16;
  return (u16)r;
}

__device__ inline void async_load16(const void* g, void* l) {
  __builtin_amdgcn_global_load_lds(
      (const __attribute__((address_space(1))) void*)g,
      (__attribute__((address_space(3))) void*)l, 16, 0, 0);
}

// XCD-aware bijective block remap; requires gridDim.x*gridDim.y % 8 == 0.
__device__ inline void xcd_remap(int& bx, int& by) {
  int gx = gridDim.x;
  int nwg = gx * gridDim.y;
  int flat = by * gx + bx;
  int swz = (flat & 7) * (nwg >> 3) + (flat >> 3);
  bx = swz % gx;
  by = swz / gx;
}

// ---------------- f32 -> bf16 elementwise (vectorized) ----------------
__global__ __launch_bounds__(256) void f32_to_bf16_k(
    const float* __restrict__ in, u16* __restrict__ out, int n4) {
  int i = blockIdx.x * 256 + threadIdx.x;
  if (i >= n4) return;
  float4 v = reinterpret_cast<const float4*>(in)[i];
  ushort4 o;
  o.x = f2bf(v.x); o.y = f2bf(v.y); o.z = f2bf(v.z); o.w = f2bf(v.w);
  reinterpret_cast<ushort4*>(out)[i] = o;
}

// ---- f32 [R][Cc] -> bf16 transposed [Cc][R]  AND bf16 non-transposed [R][Cc] ----
__global__ __launch_bounds__(256) void transpose_f32_bf16_k(
    const float* __restrict__ in, u16* __restrict__ out_t,
    u16* __restrict__ out_nt, int R, int Cc) {
  __shared__ float tile[32][33];
  int tx = threadIdx.x & 31;
  int ty = threadIdx.x >> 5;  // 0..7
  int c = blockIdx.x * 32 + tx;
#pragma unroll
  for (int j = 0; j < 4; j++) {
    int r = blockIdx.y * 32 + ty + j * 8;
    float v = in[(size_t)r * Cc + c];
    tile[ty + j * 8][tx] = v;
    out_nt[(size_t)r * Cc + c] = f2bf(v);
  }
  __syncthreads();
  int rr = blockIdx.y * 32 + tx;
#pragma unroll
  for (int j = 0; j < 4; j++) {
    int cc = blockIdx.x * 32 + ty + j * 8;
    out_t[(size_t)cc * R + rr] = f2bf(tile[tx][ty + j * 8]);
  }
}

// ---- row softmax: fp32 scores [rows][C] -> bf16 probs packed into the ----
// ---- second half of each row's own fp32 region (in-place, race-free)  ----
__global__ __launch_bounds__(256) void softmax_rows_k(
    const float* __restrict__ S, u16* __restrict__ P, int C) {
  const float4* src = reinterpret_cast<const float4*>(S + (size_t)blockIdx.x * C);
  ushort4* dst = reinterpret_cast<ushort4*>(P + (size_t)blockIdx.x * 2 * C);
  const int t = threadIdx.x;
  float4 v[4];
  float mx = -3.4e38f;
#pragma unroll
  for (int j = 0; j < 4; j++) {
    v[j] = src[j * 256 + t];
    mx = fmaxf(mx, fmaxf(fmaxf(v[j].x, v[j].y), fmaxf(v[j].z, v[j].w)));
  }
#pragma unroll
  for (int i = 1; i < 64; i <<= 1) mx = fmaxf(mx, __shfl_xor(mx, i));
  __shared__ float red[8];
  if ((t & 63) == 0) red[t >> 6] = mx;
  __syncthreads();
  mx = fmaxf(fmaxf(red[0], red[1]), fmaxf(red[2], red[3]));
  float e[16];
  float sum = 0.f;
#pragma unroll
  for (int j = 0; j < 4; j++) {
    e[j * 4 + 0] = __expf(v[j].x - mx);
    e[j * 4 + 1] = __expf(v[j].y - mx);
    e[j * 4 + 2] = __expf(v[j].z - mx);
    e[j * 4 + 3] = __expf(v[j].w - mx);
    sum += (e[j * 4 + 0] + e[j * 4 + 1]) + (e[j * 4 + 2] + e[j * 4 + 3]);
  }
#pragma unroll
  for (int i = 1; i < 64; i <<= 1) sum += __shfl_xor(sum, i);
  if ((t & 63) == 0) red[4 + (t >> 6)] = sum;
  __syncthreads();
  sum = (red[4] + red[5]) + (red[6] + red[7]);
  float inv = 1.0f / sum;
#pragma unroll
  for (int j = 0; j < 4; j++) {
    ushort4 o;
    o.x = f2bf(e[j * 4 + 0] * inv);
    o.y = f2bf(e[j * 4 + 1] * inv);
    o.z = f2bf(e[j * 4 + 2] * inv);
    o.w = f2bf(e[j * 4 + 3] * inv);
    dst[j * 256 + t] = o;
  }
}

// ======== 256x256 8-phase bf16 GEMM (8 waves, BK=64), B^T: C = A*B^T ========
// 4 phases per K-tile, Gray quadrant order (h,v)=(00)(01)(11)(10).
// Half-tiles staged in need-order A0,B0,B1,A1 (bit-striped rows); each phase's
// vmcnt proves its half landed; loads are never drained in the main loop.
// Final K-tile is PEELED: with no new stage issues, the steady-state vmcnt(4)
// no longer retires B1/A1 (exactly 4 outstanding -> no-op), so the peel uses
// the drain ladder vmcnt(4)/(2)/(0).
// Chunk-XOR swizzle cs^(row&7): pre-swizzled global source + same XOR on
// ds_read (LDS dest stays linear for global_load_lds); per-16-lane subgroup
// bank aliasing is 2-way max (free).
template <int EPI>
__global__ __launch_bounds__(512, 2) void gemm_bt256p_k(
    const u16* __restrict__ A, const u16* __restrict__ B,
    int M, int N, int K, int lda,
    float* __restrict__ outF, u16* __restrict__ outBF,
    const float* __restrict__ aux) {
  __shared__ u16 sA[2][256 * 64];   // 64 KB
  __shared__ u16 sB[2][256 * 64];   // 64 KB

  int bx = blockIdx.x, by = blockIdx.y;
  xcd_remap(bx, by);
  const int mBase = by * 256, nBase = bx * 256;

  const int tid = threadIdx.x;     // 0..511
  const int l = tid & 63;
  const int w = tid >> 6;          // 0..7
  const int wr = w >> 2;           // 0..1 (128-row half)
  const int wc = w & 3;            // 0..3 (64-col quarter)
  const int fr = l & 15;
  const int kc4 = l >> 4;          // 0..3

  f32x4 acc[8][4];
#pragma unroll
  for (int m = 0; m < 8; m++)
#pragma unroll
    for (int n = 0; n < 4; n++) acc[m][n] = (f32x4)0.f;

  // A-half h = rows with bit6==h (the rows quadrant-group h needs, both wr's).
  auto stageA = [&](int buf, int k0, int h) {
#pragma unroll
    for (int q = 0; q < 2; q++) {
      int cc = q * 512 + tid;                 // 1024 chunks per half
      int lr = cc >> 3, cs = cc & 7;
      int gr = (lr & 63) | (h << 6) | ((lr >> 6) << 7);
      int kc = (cs ^ (gr & 7)) << 3;          // source pre-swizzle
      async_load16(&A[(size_t)(mBase + gr) * lda + k0 + kc],
                   &sA[buf][gr * 64 + cs * 8]);
    }
  };
  // B-half v = rows with bit5==v.
  auto stageB = [&](int buf, int k0, int v) {
#pragma unroll
    for (int q = 0; q < 2; q++) {
      int cc = q * 512 + tid;
      int lr = cc >> 3, cs = cc & 7;
      int gr = (lr & 31) | (v << 5) | ((lr >> 5) << 6);
      int kc = (cs ^ (gr & 7)) << 3;
      async_load16(&B[(size_t)(nBase + gr) * K + k0 + kc],
                   &sB[buf][gr * 64 + cs * 8]);
    }
  };

  const int nt = K / 64;           // >= 2 for all our shapes
  // prologue: tile 0 halves in need order (8 loads in flight per wave)
  stageA(0, 0, 0); stageB(0, 0, 0); stageB(0, 0, 1); stageA(0, 0, 1);

  short8 a[4][2], b0[2][2], b1[2][2];

  // ---------------- main loop: always stages tile T+1 ----------------
  for (int T = 0; T < nt - 1; ++T) {
    const int buf = T & 1;
    const u16* sa = sA[buf];
    const u16* sb = sB[buf];
    const int k1 = (T + 1) * 64;

    // ---- P1: needs A0,B0 (B1,A1 of this tile may still fly) ----
    asm volatile("s_waitcnt vmcnt(4)" ::: "memory");
    __builtin_amdgcn_s_barrier();
#pragma unroll
    for (int mm = 0; mm < 4; mm++) {
      int row = wr * 128 + mm * 16 + fr;
#pragma unroll
      for (int kk = 0; kk < 2; kk++)
        a[mm][kk] = *reinterpret_cast<const short8*>(
            &sa[row * 64 + (((kk * 4 + kc4) ^ (row & 7)) << 3)]);
    }
#pragma unroll
    for (int nn = 0; nn < 2; nn++) {
      int row = wc * 64 + nn * 16 + fr;
#pragma unroll
      for (int kk = 0; kk < 2; kk++)
        b0[nn][kk] = *reinterpret_cast<const short8*>(
            &sb[row * 64 + (((kk * 4 + kc4) ^ (row & 7)) << 3)]);
    }
    stageA(buf ^ 1, k1, 0);
    __builtin_amdgcn_s_setprio(1);
#pragma unroll
    for (int mm = 0; mm < 4; mm++)
#pragma unroll
      for (int nn = 0; nn < 2; nn++)
#pragma unroll
        for (int kk = 0; kk < 2; kk++)
          acc[mm][nn] = __builtin_amdgcn_mfma_f32_16x16x32_bf16(
              a[mm][kk], b0[nn][kk], acc[mm][nn], 0, 0, 0);
    __builtin_amdgcn_s_setprio(0);

    // ---- P2: needs B1 ----
    asm volatile("s_waitcnt vmcnt(4)" ::: "memory");
    __builtin_amdgcn_s_barrier();
#pragma unroll
    for (int nn = 0; nn < 2; nn++) {
      int row = wc * 64 + 32 + nn * 16 + fr;
#pragma unroll
      for (int kk = 0; kk < 2; kk++)
        b1[nn][kk] = *reinterpret_cast<const short8*>(
            &sb[row * 64 + (((kk * 4 + kc4) ^ (row & 7)) << 3)]);
    }
    stageB(buf ^ 1, k1, 0);
    __builtin_amdgcn_s_setprio(1);
#pragma unroll
    for (int mm = 0; mm < 4; mm++)
#pragma unroll
      for (int nn = 0; nn < 2; nn++)
#pragma unroll
        for (int kk = 0; kk < 2; kk++)
          acc[mm][2 + nn] = __builtin_amdgcn_mfma_f32_16x16x32_bf16(
              a[mm][kk], b1[nn][kk], acc[mm][2 + nn], 0, 0, 0);
    __builtin_amdgcn_s_setprio(0);

    // ---- P3: needs A1 ----
    asm volatile("s_waitcnt vmcnt(4)" ::: "memory");
    __builtin_amdgcn_s_barrier();
#pragma unroll
    for (int mm = 0; mm < 4; mm++) {
      int row = wr * 128 + 64 + mm * 16 + fr;
#pragma unroll
      for (int kk = 0; kk < 2; kk++)
        a[mm][kk] = *reinterpret_cast<const short8*>(
            &sa[row * 64 + (((kk * 4 + kc4) ^ (row & 7)) << 3)]);
    }
    stageB(buf ^ 1, k1, 1);
    __builtin_amdgcn_s_setprio(1);
#pragma unroll
    for (int mm = 0; mm < 4; mm++)
#pragma unroll
      for (int nn = 0; nn < 2; nn++)
#pragma unroll
        for (int kk = 0; kk < 2; kk++)
          acc[4 + mm][2 + nn] = __builtin_amdgcn_mfma_f32_16x16x32_bf16(
              a[mm][kk], b1[nn][kk], acc[4 + mm][2 + nn], 0, 0, 0);
    __builtin_amdgcn_s_setprio(0);

    // ---- P4: no new reads (a=A1, b0 still live) ----
    stageA(buf ^ 1, k1, 1);
    __builtin_amdgcn_s_setprio(1);
#pragma unroll
    for (int mm = 0; mm < 4; mm++)
#pragma unroll
      for (int nn = 0; nn < 2; nn++)
#pragma unroll
        for (int kk = 0; kk < 2; kk++)
          acc[4 + mm][nn] = __builtin_amdgcn_mfma_f32_16x16x32_bf16(
              a[mm][kk], b0[nn][kk], acc[4 + mm][nn], 0, 0, 0);
    __builtin_amdgcn_s_setprio(0);
  }

  // ---------------- peeled final K-tile: drain ladder, no staging ----------------
  {
    const int buf = (nt - 1) & 1;
    const u16* sa = sA[buf];
    const u16* sb = sB[buf];

    // P1: 8 outstanding -> vmcnt(4) retires A0,B0
    asm volatile("s_waitcnt vmcnt(4)" ::: "memory");
    __builtin_amdgcn_s_barrier();
#pragma unroll
    for (int mm = 0; mm < 4; mm++) {
      int row = wr * 128 + mm * 16 + fr;
#pragma unroll
      for (int kk = 0; kk < 2; kk++)
        a[mm][kk] = *reinterpret_cast<const short8*>(
            &sa[row * 64 + (((kk * 4 + kc4) ^ (row & 7)) << 3)]);
    }
#pragma unroll
    for (int nn = 0; nn < 2; nn++) {
      int row = wc * 64 + nn * 16 + fr;
#pragma unroll
      for (int kk = 0; kk < 2; kk++)
        b0[nn][kk] = *reinterpret_cast<const short8*>(
            &sb[row * 64 + (((kk * 4 + kc4) ^ (row & 7)) << 3)]);
    }
    __builtin_amdgcn_s_setprio(1);
#pragma unroll
    for (int mm = 0; mm < 4; mm++)
#pragma unroll
      for (int nn = 0; nn < 2; nn++)
#pragma unroll
        for (int kk = 0; kk < 2; kk++)
          acc[mm][nn] = __builtin_amdgcn_mfma_f32_16x16x32_bf16(
              a[mm][kk], b0[nn][kk], acc[mm][nn], 0, 0, 0);
    __builtin_amdgcn_s_setprio(0);

    // P2: 4 outstanding -> vmcnt(2) retires B1
    asm volatile("s_waitcnt vmcnt(2)" ::: "memory");
    __builtin_amdgcn_s_barrier();
#pragma unroll
    for (int nn = 0; nn < 2; nn++) {
      int row = wc * 64 + 32 + nn * 16 + fr;
#pragma unroll
      for (int kk = 0; kk < 2; kk++)
        b1[nn][kk] = *reinterpret_cast<const short8*>(
            &sb[row * 64 + (((kk * 4 + kc4) ^ (row & 7)) << 3)]);
    }
    __builtin_amdgcn_s_setprio(1);
#pragma unroll
    for (int mm = 0; mm < 4; mm++)
#pragma unroll
      for (int nn = 0; nn < 2; nn++)
#pragma unroll
        for (int kk = 0; kk < 2; kk++)
          acc[mm][2 + nn] = __builtin_amdgcn_mfma_f32_16x16x32_bf16(
              a[mm][kk], b1[nn][kk], acc[mm][2 + nn], 0, 0, 0);
    __builtin_amdgcn_s_setprio(0);

    // P3: 2 outstanding -> vmcnt(0) retires A1
    asm volatile("s_waitcnt vmcnt(0)" ::: "memory");
    __builtin_amdgcn_s_barrier();
#pragma unroll
    for (int mm = 0; mm < 4; mm++) {
      int row = wr * 128 + 64 + mm * 16 + fr;
#pragma unroll
      for (int kk = 0; kk < 2; kk++)
        a[mm][kk] = *reinterpret_cast<const short8*>(
            &sa[row * 64 + (((kk * 4 + kc4) ^ (row & 7)) << 3)]);
    }
    __builtin_amdgcn_s_setprio(1);
#pragma unroll
    for (int mm = 0; mm < 4; mm++)
#pragma unroll
      for (int nn = 0; nn < 2; nn++)
#pragma unroll
        for (int kk = 0; kk < 2; kk++)
          acc[4 + mm][2 + nn] = __builtin_amdgcn_mfma_f32_16x16x32_bf16(
              a[mm][kk], b1[nn][kk], acc[4 + mm][2 + nn], 0, 0, 0);
    __builtin_amdgcn_s_setprio(0);

    // P4: regs only
    __builtin_amdgcn_s_setprio(1);
#pragma unroll
    for (int mm = 0; mm < 4; mm++)
#pragma unroll
      for (int nn = 0; nn < 2; nn++)
#pragma unroll
        for (int kk = 0; kk < 2; kk++)
          acc[4 + mm][nn] = __builtin_amdgcn_mfma_f32_16x16x32_bf16(
              a[mm][kk], b0[nn][kk], acc[4 + mm][nn], 0, 0, 0);
    __builtin_amdgcn_s_setprio(0);
  }

  // epilogue: row = mBase + wr*128 + m*16 + (l>>4)*4 + r, col = nBase + wc*64 + n*16 + fr
#pragma unroll
  for (int m = 0; m < 8; m++) {
#pragma unroll
    for (int n = 0; n < 4; n++) {
      int col = nBase + wc * 64 + n * 16 + fr;
#pragma unroll
      for (int r = 0; r < 4; r++) {
        int row = mBase + wr * 128 + m * 16 + (l >> 4) * 4 + r;
        size_t o = (size_t)row * N + col;
        float v = acc[m][n][r];
        if (EPI == 0) {
          outF[o] = v;
        } else if (EPI == 1) {
          outBF[o] = f2bf(v + aux[o]);
        } else {
          v += aux[col];
          outF[o] = (v >= 0.f) ? v : 0.01f * v;
        }
      }
    }
  }
}

// ============ 128x128 tile bf16 GEMM (4 waves), 4-slot ring (round-5) ============
template <int EPI>
__global__ __launch_bounds__(256, 2) void gemm_bt_k(
    const u16* __restrict__ A, const u16* __restrict__ B,
    int M, int N, int K, int lda,
    float* __restrict__ outF, u16* __restrict__ outBF,
    const float* __restrict__ aux) {
  __shared__ u16 sA[4][128 * 32];
  __shared__ u16 sB[4][128 * 32];

  int bx = blockIdx.x, by = blockIdx.y;
  xcd_remap(bx, by);
  const int mBase = by * 128;
  const int nBase = bx * 128;

  const int tid = threadIdx.x;
  const int l = tid & 63;
  const int w = tid >> 6;
  const int wr = w >> 1;
  const int wc = w & 1;
  const int fr = l & 15;
  const int kc4 = l >> 4;

  f32x4 acc[4][4];
#pragma unroll
  for (int m = 0; m < 4; m++)
#pragma unroll
    for (int n = 0; n < 4; n++) acc[m][n] = (f32x4)0.f;

  auto stage = [&](int slot, int k0) {
#pragma unroll
    for (int q = 0; q < 2; q++) {
      int c = q * 256 + tid;
      int row = c >> 2;
      int cs = c & 3;
      int kc = ((cs ^ ((row >> 1) & 3)) << 3);
      async_load16(&A[(size_t)(mBase + row) * lda + k0 + kc], &sA[slot][c * 8]);
      async_load16(&B[(size_t)(nBase + row) * K + k0 + kc], &sB[slot][c * 8]);
    }
  };

  const int nt = K / 32;
  stage(0, 0); stage(1, 32); stage(2, 64); stage(3, 96);

  for (int t = 0; t < nt; ++t) {
    asm volatile("s_waitcnt vmcnt(12)" ::: "memory");
    __builtin_amdgcn_s_barrier();

    const u16* sa = sA[t & 3];
    const u16* sb = sB[t & 3];
    short8 af[4], bf[4];
#pragma unroll
    for (int m = 0; m < 4; m++) {
      int row = wr * 64 + m * 16 + fr;
      af[m] = *reinterpret_cast<const short8*>(
          &sa[row * 32 + ((kc4 ^ ((row >> 1) & 3)) << 3)]);
    }
#pragma unroll
    for (int n = 0; n < 4; n++) {
      int row = wc * 64 + n * 16 + fr;
      bf[n] = *reinterpret_cast<const short8*>(
          &sb[row * 32 + ((kc4 ^ ((row >> 1) & 3)) << 3)]);
    }

    __builtin_amdgcn_s_setprio(1);
#pragma unroll
    for (int m = 0; m < 4; m++)
#pragma unroll
      for (int n = 0; n < 4; n++)
        acc[m][n] = __builtin_amdgcn_mfma_f32_16x16x32_bf16(af[m], bf[n], acc[m][n], 0, 0, 0);
    __builtin_amdgcn_s_setprio(0);

    asm volatile("s_waitcnt lgkmcnt(0)" ::: "memory");
    __builtin_amdgcn_s_barrier();
    if (t + 4 < nt) stage((t + 4) & 3, (t + 4) * 32);
  }

#pragma unroll
  for (int m = 0; m < 4; m++) {
#pragma unroll
    for (int n = 0; n < 4; n++) {
      int col = nBase + wc * 64 + n * 16 + fr;
#pragma unroll
      for (int r = 0; r < 4; r++) {
        int row = mBase + wr * 64 + m * 16 + (l >> 4) * 4 + r;
        size_t o = (size_t)row * N + col;
        float v = acc[m][n][r];
        if (EPI == 0) {
          outF[o] = v;
        } else if (EPI == 1) {
          outBF[o] = f2bf(v + aux[o]);
        } else {
          v += aux[col];
          outF[o] = (v >= 0.f) ? v : 0.01f * v;
        }
      }
    }
  }
}

extern "C" void kernel_launch(void* const* d_in, const int* in_sizes, int n_in,
                              void* d_out, int out_size, void* d_ws, size_t ws_size,
                              hipStream_t stream) {
  const float* x = (const float*)d_in[0];     // [Mrows, D]
  const float* E = (const float*)d_in[1];     // [C, D]
  const float* W = (const float*)d_in[2];     // [C, D]
  const float* bias = (const float*)d_in[3];  // [C]

  const int C = in_sizes[3];              // 4096
  const int D = in_sizes[1] / C;          // 1024
  const int Mrows = in_sizes[0] / D;      // 8192

  char* p = (char*)d_ws;
  u16* xbf = (u16*)p;   p += (size_t)Mrows * D * 2;   // 16 MB
  u16* Ebf = (u16*)p;   p += (size_t)C * D * 2;       // 8 MB
  u16* Etbf = (u16*)p;  p += (size_t)C * D * 2;       // 8 MB (E^T: [D][C])
  u16* Wbf = (u16*)p;   p += (size_t)C * D * 2;       // 8 MB
  u16* x2bf = (u16*)p;  p += (size_t)Mrows * D * 2;   // 16 MB
  float* scores = (float*)p;                          // 128 MB (probs packed inside)
  u16* probs = (u16*)scores + C;   // probs row r at u16 r*2C + C; lda = 2*C

  // 1) conversions (E's bf16 copy fused into the transpose kernel)
  {
    int n4 = Mrows * D / 4;
    f32_to_bf16_k<<<(n4 + 255) / 256, 256, 0, stream>>>(x, xbf, n4);
  }
  {
    int n4 = C * D / 4;
    f32_to_bf16_k<<<(n4 + 255) / 256, 256, 0, stream>>>(W, Wbf, n4);
  }
  transpose_f32_bf16_k<<<dim3(D / 32, C / 32), 256, 0, stream>>>(E, Etbf, Ebf, C, D);

  // 2) scores = x @ E^T   [Mrows, C] fp32   (8-phase 256^2: 16x32 = 512 blocks)
  gemm_bt256p_k<0><<<dim3(C / 256, Mrows / 256), 512, 0, stream>>>(
      xbf, Ebf, Mrows, C, D, D, scores, nullptr, nullptr);

  // 3) probs = softmax(scores) -> bf16, packed in-place
  softmax_rows_k<<<Mrows, 256, 0, stream>>>(scores, probs, C);

  // 4) x2 = x + probs @ E   [Mrows, D] bf16   (A = probs, lda = 2C)
  gemm_bt_k<1><<<dim3(D / 128, Mrows / 128), 256, 0, stream>>>(
      probs, Etbf, Mrows, D, C, 2 * C, nullptr, x2bf, x);

  // 5) out = leakyrelu(x2 @ W^T + b)  [Mrows, C] fp32  (8-phase 256^2)
  gemm_bt256p_k<2><<<dim3(C / 256, Mrows / 256), 512, 0, stream>>>(
      x2bf, Wbf, Mrows, C, D, D, (float*)d_out, nullptr, bias);
}

// Round 9
// 416.930 us; speedup vs baseline: 1.2900x; 1.0519x over previous
//
#include <hip/hip_runtime.h>
#include <hip/hip_bf16.h>
#include <stdint.h>

typedef unsigned short u16;
typedef __attribute__((ext_vector_type(8))) short short8;   // 8 bf16 (4 VGPRs)
typedef __attribute__((ext_vector_type(4))) float f32x4;

__device__ inline u16 f2bf(float f) {
  union { float f; uint32_t u; } x; x.f = f;
  uint32_t r = (x.u + 0x7FFFu + ((x.u >> 16) & 1u)) >> 16;
  return (u16)r;
}

__device__ inline void async_load16(const void* g, void* l) {
  __builtin_amdgcn_global_load_lds(
      (const __attribute__((address_space(1))) void*)g,
      (__attribute__((address_space(3))) void*)l, 16, 0, 0);
}

// XCD-aware bijective block remap; requires gridDim.x*gridDim.y % 8 == 0.
__device__ inline void xcd_remap(int& bx, int& by) {
  int gx = gridDim.x;
  int nwg = gx * gridDim.y;
  int flat = by * gx + bx;
  int swz = (flat & 7) * (nwg >> 3) + (flat >> 3);
  bx = swz % gx;
  by = swz / gx;
}

// ---- fused prep: x f32->bf16 | W f32->bf16 | E f32 -> Ebf + Etbf (transpose) ----
// block roles by range: [0,nbx) x-convert, [nbx,nbx+nbw) W-convert, rest transpose.
__global__ __launch_bounds__(256) void prep_k(
    const float* __restrict__ x, u16* __restrict__ xbf, int n4x, int nbx,
    const float* __restrict__ W, u16* __restrict__ Wbf, int n4w, int nbw,
    const float* __restrict__ E, u16* __restrict__ Ebf, u16* __restrict__ Etbf,
    int R, int Cc) {
  __shared__ float tile[32][33];
  const int b = blockIdx.x;
  const int t = threadIdx.x;
  if (b < nbx) {
#pragma unroll
    for (int j = 0; j < 4; j++) {
      int i = b * 1024 + j * 256 + t;
      if (i < n4x) {
        float4 v = reinterpret_cast<const float4*>(x)[i];
        ushort4 o;
        o.x = f2bf(v.x); o.y = f2bf(v.y); o.z = f2bf(v.z); o.w = f2bf(v.w);
        reinterpret_cast<ushort4*>(xbf)[i] = o;
      }
    }
  } else if (b < nbx + nbw) {
    int bb = b - nbx;
#pragma unroll
    for (int j = 0; j < 4; j++) {
      int i = bb * 1024 + j * 256 + t;
      if (i < n4w) {
        float4 v = reinterpret_cast<const float4*>(W)[i];
        ushort4 o;
        o.x = f2bf(v.x); o.y = f2bf(v.y); o.z = f2bf(v.z); o.w = f2bf(v.w);
        reinterpret_cast<ushort4*>(Wbf)[i] = o;
      }
    }
  } else {
    int bb = b - nbx - nbw;
    int gbx = bb % (Cc / 32);     // col-tile of E (over D)
    int gby = bb / (Cc / 32);     // row-tile of E (over C)
    int tx = t & 31;
    int ty = t >> 5;              // 0..7
    int c = gbx * 32 + tx;
#pragma unroll
    for (int j = 0; j < 4; j++) {
      int r = gby * 32 + ty + j * 8;
      float v = E[(size_t)r * Cc + c];
      tile[ty + j * 8][tx] = v;
      Ebf[(size_t)r * Cc + c] = f2bf(v);
    }
    __syncthreads();
    int rr = gby * 32 + tx;
#pragma unroll
    for (int j = 0; j < 4; j++) {
      int cc = gbx * 32 + ty + j * 8;
      Etbf[(size_t)cc * R + rr] = f2bf(tile[tx][ty + j * 8]);
    }
  }
}

// ---- row softmax: fp32 scores [rows][C] -> bf16 probs packed into the ----
// ---- second half of each row's own fp32 region (in-place, race-free)  ----
__global__ __launch_bounds__(256) void softmax_rows_k(
    const float* __restrict__ S, u16* __restrict__ P, int C) {
  const float4* src = reinterpret_cast<const float4*>(S + (size_t)blockIdx.x * C);
  ushort4* dst = reinterpret_cast<ushort4*>(P + (size_t)blockIdx.x * 2 * C);
  const int t = threadIdx.x;
  float4 v[4];
  float mx = -3.4e38f;
#pragma unroll
  for (int j = 0; j < 4; j++) {
    v[j] = src[j * 256 + t];
    mx = fmaxf(mx, fmaxf(fmaxf(v[j].x, v[j].y), fmaxf(v[j].z, v[j].w)));
  }
#pragma unroll
  for (int i = 1; i < 64; i <<= 1) mx = fmaxf(mx, __shfl_xor(mx, i));
  __shared__ float red[8];
  if ((t & 63) == 0) red[t >> 6] = mx;
  __syncthreads();
  mx = fmaxf(fmaxf(red[0], red[1]), fmaxf(red[2], red[3]));
  float e[16];
  float sum = 0.f;
#pragma unroll
  for (int j = 0; j < 4; j++) {
    e[j * 4 + 0] = __expf(v[j].x - mx);
    e[j * 4 + 1] = __expf(v[j].y - mx);
    e[j * 4 + 2] = __expf(v[j].z - mx);
    e[j * 4 + 3] = __expf(v[j].w - mx);
    sum += (e[j * 4 + 0] + e[j * 4 + 1]) + (e[j * 4 + 2] + e[j * 4 + 3]);
  }
#pragma unroll
  for (int i = 1; i < 64; i <<= 1) sum += __shfl_xor(sum, i);
  if ((t & 63) == 0) red[4 + (t >> 6)] = sum;
  __syncthreads();
  sum = (red[4] + red[5]) + (red[6] + red[7]);
  float inv = 1.0f / sum;
#pragma unroll
  for (int j = 0; j < 4; j++) {
    ushort4 o;
    o.x = f2bf(e[j * 4 + 0] * inv);
    o.y = f2bf(e[j * 4 + 1] * inv);
    o.z = f2bf(e[j * 4 + 2] * inv);
    o.w = f2bf(e[j * 4 + 3] * inv);
    dst[j * 256 + t] = o;
  }
}

// ======== 256x256 8-phase bf16 GEMM (8 waves, BK=64), B^T: C = A*B^T ========
// (unchanged from round 8 — verified correct, ~763 TF)
template <int EPI>
__global__ __launch_bounds__(512, 2) void gemm_bt256p_k(
    const u16* __restrict__ A, const u16* __restrict__ B,
    int M, int N, int K, int lda,
    float* __restrict__ outF, u16* __restrict__ outBF,
    const float* __restrict__ aux) {
  __shared__ u16 sA[2][256 * 64];   // 64 KB
  __shared__ u16 sB[2][256 * 64];   // 64 KB

  int bx = blockIdx.x, by = blockIdx.y;
  xcd_remap(bx, by);
  const int mBase = by * 256, nBase = bx * 256;

  const int tid = threadIdx.x;     // 0..511
  const int l = tid & 63;
  const int w = tid >> 6;          // 0..7
  const int wr = w >> 2;           // 0..1 (128-row half)
  const int wc = w & 3;            // 0..3 (64-col quarter)
  const int fr = l & 15;
  const int kc4 = l >> 4;          // 0..3

  f32x4 acc[8][4];
#pragma unroll
  for (int m = 0; m < 8; m++)
#pragma unroll
    for (int n = 0; n < 4; n++) acc[m][n] = (f32x4)0.f;

  auto stageA = [&](int buf, int k0, int h) {
#pragma unroll
    for (int q = 0; q < 2; q++) {
      int cc = q * 512 + tid;                 // 1024 chunks per half
      int lr = cc >> 3, cs = cc & 7;
      int gr = (lr & 63) | (h << 6) | ((lr >> 6) << 7);
      int kc = (cs ^ (gr & 7)) << 3;          // source pre-swizzle
      async_load16(&A[(size_t)(mBase + gr) * lda + k0 + kc],
                   &sA[buf][gr * 64 + cs * 8]);
    }
  };
  auto stageB = [&](int buf, int k0, int v) {
#pragma unroll
    for (int q = 0; q < 2; q++) {
      int cc = q * 512 + tid;
      int lr = cc >> 3, cs = cc & 7;
      int gr = (lr & 31) | (v << 5) | ((lr >> 5) << 6);
      int kc = (cs ^ (gr & 7)) << 3;
      async_load16(&B[(size_t)(nBase + gr) * K + k0 + kc],
                   &sB[buf][gr * 64 + cs * 8]);
    }
  };

  const int nt = K / 64;
  stageA(0, 0, 0); stageB(0, 0, 0); stageB(0, 0, 1); stageA(0, 0, 1);

  short8 a[4][2], b0[2][2], b1[2][2];

  for (int T = 0; T < nt - 1; ++T) {
    const int buf = T & 1;
    const u16* sa = sA[buf];
    const u16* sb = sB[buf];
    const int k1 = (T + 1) * 64;

    // ---- P1: needs A0,B0 ----
    asm volatile("s_waitcnt vmcnt(4)" ::: "memory");
    __builtin_amdgcn_s_barrier();
#pragma unroll
    for (int mm = 0; mm < 4; mm++) {
      int row = wr * 128 + mm * 16 + fr;
#pragma unroll
      for (int kk = 0; kk < 2; kk++)
        a[mm][kk] = *reinterpret_cast<const short8*>(
            &sa[row * 64 + (((kk * 4 + kc4) ^ (row & 7)) << 3)]);
    }
#pragma unroll
    for (int nn = 0; nn < 2; nn++) {
      int row = wc * 64 + nn * 16 + fr;
#pragma unroll
      for (int kk = 0; kk < 2; kk++)
        b0[nn][kk] = *reinterpret_cast<const short8*>(
            &sb[row * 64 + (((kk * 4 + kc4) ^ (row & 7)) << 3)]);
    }
    stageA(buf ^ 1, k1, 0);
    __builtin_amdgcn_s_setprio(1);
#pragma unroll
    for (int mm = 0; mm < 4; mm++)
#pragma unroll
      for (int nn = 0; nn < 2; nn++)
#pragma unroll
        for (int kk = 0; kk < 2; kk++)
          acc[mm][nn] = __builtin_amdgcn_mfma_f32_16x16x32_bf16(
              a[mm][kk], b0[nn][kk], acc[mm][nn], 0, 0, 0);
    __builtin_amdgcn_s_setprio(0);

    // ---- P2: needs B1 ----
    asm volatile("s_waitcnt vmcnt(4)" ::: "memory");
    __builtin_amdgcn_s_barrier();
#pragma unroll
    for (int nn = 0; nn < 2; nn++) {
      int row = wc * 64 + 32 + nn * 16 + fr;
#pragma unroll
      for (int kk = 0; kk < 2; kk++)
        b1[nn][kk] = *reinterpret_cast<const short8*>(
            &sb[row * 64 + (((kk * 4 + kc4) ^ (row & 7)) << 3)]);
    }
    stageB(buf ^ 1, k1, 0);
    __builtin_amdgcn_s_setprio(1);
#pragma unroll
    for (int mm = 0; mm < 4; mm++)
#pragma unroll
      for (int nn = 0; nn < 2; nn++)
#pragma unroll
        for (int kk = 0; kk < 2; kk++)
          acc[mm][2 + nn] = __builtin_amdgcn_mfma_f32_16x16x32_bf16(
              a[mm][kk], b1[nn][kk], acc[mm][2 + nn], 0, 0, 0);
    __builtin_amdgcn_s_setprio(0);

    // ---- P3: needs A1 ----
    asm volatile("s_waitcnt vmcnt(4)" ::: "memory");
    __builtin_amdgcn_s_barrier();
#pragma unroll
    for (int mm = 0; mm < 4; mm++) {
      int row = wr * 128 + 64 + mm * 16 + fr;
#pragma unroll
      for (int kk = 0; kk < 2; kk++)
        a[mm][kk] = *reinterpret_cast<const short8*>(
            &sa[row * 64 + (((kk * 4 + kc4) ^ (row & 7)) << 3)]);
    }
    stageB(buf ^ 1, k1, 1);
    __builtin_amdgcn_s_setprio(1);
#pragma unroll
    for (int mm = 0; mm < 4; mm++)
#pragma unroll
      for (int nn = 0; nn < 2; nn++)
#pragma unroll
        for (int kk = 0; kk < 2; kk++)
          acc[4 + mm][2 + nn] = __builtin_amdgcn_mfma_f32_16x16x32_bf16(
              a[mm][kk], b1[nn][kk], acc[4 + mm][2 + nn], 0, 0, 0);
    __builtin_amdgcn_s_setprio(0);

    // ---- P4: no new reads ----
    stageA(buf ^ 1, k1, 1);
    __builtin_amdgcn_s_setprio(1);
#pragma unroll
    for (int mm = 0; mm < 4; mm++)
#pragma unroll
      for (int nn = 0; nn < 2; nn++)
#pragma unroll
        for (int kk = 0; kk < 2; kk++)
          acc[4 + mm][nn] = __builtin_amdgcn_mfma_f32_16x16x32_bf16(
              a[mm][kk], b0[nn][kk], acc[4 + mm][nn], 0, 0, 0);
    __builtin_amdgcn_s_setprio(0);
  }

  // ---------------- peeled final K-tile: drain ladder ----------------
  {
    const int buf = (nt - 1) & 1;
    const u16* sa = sA[buf];
    const u16* sb = sB[buf];

    asm volatile("s_waitcnt vmcnt(4)" ::: "memory");
    __builtin_amdgcn_s_barrier();
#pragma unroll
    for (int mm = 0; mm < 4; mm++) {
      int row = wr * 128 + mm * 16 + fr;
#pragma unroll
      for (int kk = 0; kk < 2; kk++)
        a[mm][kk] = *reinterpret_cast<const short8*>(
            &sa[row * 64 + (((kk * 4 + kc4) ^ (row & 7)) << 3)]);
    }
#pragma unroll
    for (int nn = 0; nn < 2; nn++) {
      int row = wc * 64 + nn * 16 + fr;
#pragma unroll
      for (int kk = 0; kk < 2; kk++)
        b0[nn][kk] = *reinterpret_cast<const short8*>(
            &sb[row * 64 + (((kk * 4 + kc4) ^ (row & 7)) << 3)]);
    }
    __builtin_amdgcn_s_setprio(1);
#pragma unroll
    for (int mm = 0; mm < 4; mm++)
#pragma unroll
      for (int nn = 0; nn < 2; nn++)
#pragma unroll
        for (int kk = 0; kk < 2; kk++)
          acc[mm][nn] = __builtin_amdgcn_mfma_f32_16x16x32_bf16(
              a[mm][kk], b0[nn][kk], acc[mm][nn], 0, 0, 0);
    __builtin_amdgcn_s_setprio(0);

    asm volatile("s_waitcnt vmcnt(2)" ::: "memory");
    __builtin_amdgcn_s_barrier();
#pragma unroll
    for (int nn = 0; nn < 2; nn++) {
      int row = wc * 64 + 32 + nn * 16 + fr;
#pragma unroll
      for (int kk = 0; kk < 2; kk++)
        b1[nn][kk] = *reinterpret_cast<const short8*>(
            &sb[row * 64 + (((kk * 4 + kc4) ^ (row & 7)) << 3)]);
    }
    __builtin_amdgcn_s_setprio(1);
#pragma unroll
    for (int mm = 0; mm < 4; mm++)
#pragma unroll
      for (int nn = 0; nn < 2; nn++)
#pragma unroll
        for (int kk = 0; kk < 2; kk++)
          acc[mm][2 + nn] = __builtin_amdgcn_mfma_f32_16x16x32_bf16(
              a[mm][kk], b1[nn][kk], acc[mm][2 + nn], 0, 0, 0);
    __builtin_amdgcn_s_setprio(0);

    asm volatile("s_waitcnt vmcnt(0)" ::: "memory");
    __builtin_amdgcn_s_barrier();
#pragma unroll
    for (int mm = 0; mm < 4; mm++) {
      int row = wr * 128 + 64 + mm * 16 + fr;
#pragma unroll
      for (int kk = 0; kk < 2; kk++)
        a[mm][kk] = *reinterpret_cast<const short8*>(
            &sa[row * 64 + (((kk * 4 + kc4) ^ (row & 7)) << 3)]);
    }
    __builtin_amdgcn_s_setprio(1);
#pragma unroll
    for (int mm = 0; mm < 4; mm++)
#pragma unroll
      for (int nn = 0; nn < 2; nn++)
#pragma unroll
        for (int kk = 0; kk < 2; kk++)
          acc[4 + mm][2 + nn] = __builtin_amdgcn_mfma_f32_16x16x32_bf16(
              a[mm][kk], b1[nn][kk], acc[4 + mm][2 + nn], 0, 0, 0);
    __builtin_amdgcn_s_setprio(0);

    __builtin_amdgcn_s_setprio(1);
#pragma unroll
    for (int mm = 0; mm < 4; mm++)
#pragma unroll
      for (int nn = 0; nn < 2; nn++)
#pragma unroll
        for (int kk = 0; kk < 2; kk++)
          acc[4 + mm][nn] = __builtin_amdgcn_mfma_f32_16x16x32_bf16(
              a[mm][kk], b0[nn][kk], acc[4 + mm][nn], 0, 0, 0);
    __builtin_amdgcn_s_setprio(0);
  }

#pragma unroll
  for (int m = 0; m < 8; m++) {
#pragma unroll
    for (int n = 0; n < 4; n++) {
      int col = nBase + wc * 64 + n * 16 + fr;
#pragma unroll
      for (int r = 0; r < 4; r++) {
        int row = mBase + wr * 128 + m * 16 + (l >> 4) * 4 + r;
        size_t o = (size_t)row * N + col;
        float v = acc[m][n][r];
        if (EPI == 0) {
          outF[o] = v;
        } else {
          v += aux[col];
          outF[o] = (v >= 0.f) ? v : 0.01f * v;
        }
      }
    }
  }
}

// ======== GEMM2: 256x128 tile, BK=64, 2 fine phases/K-tile (8 waves) ========
// x2 = bf16(probs @ E^T_layout + x). Grid 8x32 = 256 blocks = 1/CU, no tail.
// Halves in need order: A0(2 loads), B(2), A1(2). Steady: P1 vmcnt(2) retires
// {A0,B}; stage A0'. P2 vmcnt(2) retires {A1}; stage B'+A1'. Peel: (2)/(0).
__global__ __launch_bounds__(512, 2) void gemm2_k(
    const u16* __restrict__ A, const u16* __restrict__ B,
    int M, int N, int K, int lda,
    u16* __restrict__ outBF, const float* __restrict__ aux) {
  __shared__ u16 sA[2][256 * 64];   // 64 KB
  __shared__ u16 sB[2][128 * 64];   // 32 KB

  int bx = blockIdx.x, by = blockIdx.y;
  xcd_remap(bx, by);
  const int mBase = by * 256, nBase = bx * 128;

  const int tid = threadIdx.x;     // 0..511
  const int l = tid & 63;
  const int w = tid >> 6;          // 0..7
  const int wr = w >> 2;           // 0..1 (128-row half)
  const int wc = w & 3;            // 0..3 (32-col slice)
  const int fr = l & 15;
  const int kc4 = l >> 4;          // 0..3

  f32x4 acc[8][2];
#pragma unroll
  for (int m = 0; m < 8; m++)
#pragma unroll
    for (int n = 0; n < 2; n++) acc[m][n] = (f32x4)0.f;

  // A-half h: 128 rows with bit6==h (bit-striped), 2 load-instrs.
  auto stageA = [&](int buf, int k0, int h) {
#pragma unroll
    for (int q = 0; q < 2; q++) {
      int cc = q * 512 + tid;            // 1024 chunks per half
      int lr = cc >> 3, cs = cc & 7;
      int gr = (lr & 63) | (h << 6) | ((lr >> 6) << 7);
      int kc = (cs ^ (gr & 7)) << 3;
      async_load16(&A[(size_t)(mBase + gr) * lda + k0 + kc],
                   &sA[buf][gr * 64 + cs * 8]);
    }
  };
  // whole B tile (128 rows), 2 load-instrs.
  auto stageB = [&](int buf, int k0) {
#pragma unroll
    for (int q = 0; q < 2; q++) {
      int cc = q * 512 + tid;            // 1024 chunks
      int gr = cc >> 3, cs = cc & 7;
      int kc = (cs ^ (gr & 7)) << 3;
      async_load16(&B[(size_t)(nBase + gr) * K + k0 + kc],
                   &sB[buf][gr * 64 + cs * 8]);
    }
  };

  const int nt = K / 64;               // 64 for K=4096
  stageA(0, 0, 0); stageB(0, 0); stageA(0, 0, 1);   // 6 in flight

  short8 a[4][2], b[2][2];

  for (int T = 0; T < nt - 1; ++T) {
    const int buf = T & 1;
    const u16* sa = sA[buf];
    const u16* sb = sB[buf];
    const int k1 = (T + 1) * 64;

    // ---- P1: needs A0 + B (6 in flight, retire 4 oldest) ----
    asm volatile("s_waitcnt vmcnt(2)" ::: "memory");
    __builtin_amdgcn_s_barrier();
#pragma unroll
    for (int mm = 0; mm < 4; mm++) {
      int row = wr * 128 + mm * 16 + fr;
#pragma unroll
      for (int kk = 0; kk < 2; kk++)
        a[mm][kk] = *reinterpret_cast<const short8*>(
            &sa[row * 64 + (((kk * 4 + kc4) ^ (row & 7)) << 3)]);
    }
#pragma unroll
    for (int nn = 0; nn < 2; nn++) {
      int row = wc * 32 + nn * 16 + fr;
#pragma unroll
      for (int kk = 0; kk < 2; kk++)
        b[nn][kk] = *reinterpret_cast<const short8*>(
            &sb[row * 64 + (((kk * 4 + kc4) ^ (row & 7)) << 3)]);
    }
    stageA(buf ^ 1, k1, 0);
    __builtin_amdgcn_s_setprio(1);
#pragma unroll
    for (int mm = 0; mm < 4; mm++)
#pragma unroll
      for (int nn = 0; nn < 2; nn++)
#pragma unroll
        for (int kk = 0; kk < 2; kk++)
          acc[mm][nn] = __builtin_amdgcn_mfma_f32_16x16x32_bf16(
              a[mm][kk], b[nn][kk], acc[mm][nn], 0, 0, 0);
    __builtin_amdgcn_s_setprio(0);

    // ---- P2: needs A1 (4 in flight: A1 + A0'; retire 2 oldest) ----
    asm volatile("s_waitcnt vmcnt(2)" ::: "memory");
    __builtin_amdgcn_s_barrier();
#pragma unroll
    for (int mm = 0; mm < 4; mm++) {
      int row = wr * 128 + 64 + mm * 16 + fr;
#pragma unroll
      for (int kk = 0; kk < 2; kk++)
        a[mm][kk] = *reinterpret_cast<const short8*>(
            &sa[row * 64 + (((kk * 4 + kc4) ^ (row & 7)) << 3)]);
    }
    stageB(buf ^ 1, k1);
    stageA(buf ^ 1, k1, 1);
    __builtin_amdgcn_s_setprio(1);
#pragma unroll
    for (int mm = 0; mm < 4; mm++)
#pragma unroll
      for (int nn = 0; nn < 2; nn++)
#pragma unroll
        for (int kk = 0; kk < 2; kk++)
          acc[4 + mm][nn] = __builtin_amdgcn_mfma_f32_16x16x32_bf16(
              a[mm][kk], b[nn][kk], acc[4 + mm][nn], 0, 0, 0);
    __builtin_amdgcn_s_setprio(0);
  }

  // ---- peeled final K-tile (6 in flight at entry, no staging) ----
  {
    const int buf = (nt - 1) & 1;
    const u16* sa = sA[buf];
    const u16* sb = sB[buf];

    asm volatile("s_waitcnt vmcnt(2)" ::: "memory");   // retires A0,B
    __builtin_amdgcn_s_barrier();
#pragma unroll
    for (int mm = 0; mm < 4; mm++) {
      int row = wr * 128 + mm * 16 + fr;
#pragma unroll
      for (int kk = 0; kk < 2; kk++)
        a[mm][kk] = *reinterpret_cast<const short8*>(
            &sa[row * 64 + (((kk * 4 + kc4) ^ (row & 7)) << 3)]);
    }
#pragma unroll
    for (int nn = 0; nn < 2; nn++) {
      int row = wc * 32 + nn * 16 + fr;
#pragma unroll
      for (int kk = 0; kk < 2; kk++)
        b[nn][kk] = *reinterpret_cast<const short8*>(
            &sb[row * 64 + (((kk * 4 + kc4) ^ (row & 7)) << 3)]);
    }
    __builtin_amdgcn_s_setprio(1);
#pragma unroll
    for (int mm = 0; mm < 4; mm++)
#pragma unroll
      for (int nn = 0; nn < 2; nn++)
#pragma unroll
        for (int kk = 0; kk < 2; kk++)
          acc[mm][nn] = __builtin_amdgcn_mfma_f32_16x16x32_bf16(
              a[mm][kk], b[nn][kk], acc[mm][nn], 0, 0, 0);
    __builtin_amdgcn_s_setprio(0);

    asm volatile("s_waitcnt vmcnt(0)" ::: "memory");   // retires A1
    __builtin_amdgcn_s_barrier();
#pragma unroll
    for (int mm = 0; mm < 4; mm++) {
      int row = wr * 128 + 64 + mm * 16 + fr;
#pragma unroll
      for (int kk = 0; kk < 2; kk++)
        a[mm][kk] = *reinterpret_cast<const short8*>(
            &sa[row * 64 + (((kk * 4 + kc4) ^ (row & 7)) << 3)]);
    }
    __builtin_amdgcn_s_setprio(1);
#pragma unroll
    for (int mm = 0; mm < 4; mm++)
#pragma unroll
      for (int nn = 0; nn < 2; nn++)
#pragma unroll
        for (int kk = 0; kk < 2; kk++)
          acc[4 + mm][nn] = __builtin_amdgcn_mfma_f32_16x16x32_bf16(
              a[mm][kk], b[nn][kk], acc[4 + mm][nn], 0, 0, 0);
    __builtin_amdgcn_s_setprio(0);
  }

  // epilogue: x2 = bf16(acc + x)
#pragma unroll
  for (int m = 0; m < 8; m++) {
#pragma unroll
    for (int n = 0; n < 2; n++) {
      int col = nBase + wc * 32 + n * 16 + fr;
#pragma unroll
      for (int r = 0; r < 4; r++) {
        int row = mBase + wr * 128 + m * 16 + (l >> 4) * 4 + r;
        size_t o = (size_t)row * N + col;
        outBF[o] = f2bf(acc[m][n][r] + aux[o]);
      }
    }
  }
}

extern "C" void kernel_launch(void* const* d_in, const int* in_sizes, int n_in,
                              void* d_out, int out_size, void* d_ws, size_t ws_size,
                              hipStream_t stream) {
  const float* x = (const float*)d_in[0];     // [Mrows, D]
  const float* E = (const float*)d_in[1];     // [C, D]
  const float* W = (const float*)d_in[2];     // [C, D]
  const float* bias = (const float*)d_in[3];  // [C]

  const int C = in_sizes[3];              // 4096
  const int D = in_sizes[1] / C;          // 1024
  const int Mrows = in_sizes[0] / D;      // 8192

  char* p = (char*)d_ws;
  u16* xbf = (u16*)p;   p += (size_t)Mrows * D * 2;   // 16 MB
  u16* Ebf = (u16*)p;   p += (size_t)C * D * 2;       // 8 MB
  u16* Etbf = (u16*)p;  p += (size_t)C * D * 2;       // 8 MB (E^T: [D][C])
  u16* Wbf = (u16*)p;   p += (size_t)C * D * 2;       // 8 MB
  u16* x2bf = (u16*)p;  p += (size_t)Mrows * D * 2;   // 16 MB
  float* scores = (float*)p;                          // 128 MB (probs packed inside)
  u16* probs = (u16*)scores + C;   // probs row r at u16 r*2C + C; lda = 2*C

  // 1) fused prep: x->bf16 | W->bf16 | E -> Ebf + Etbf
  {
    int n4x = Mrows * D / 4;
    int n4w = C * D / 4;
    int nbx = (n4x + 1023) / 1024;
    int nbw = (n4w + 1023) / 1024;
    int nbt = (D / 32) * (C / 32);
    prep_k<<<nbx + nbw + nbt, 256, 0, stream>>>(
        x, xbf, n4x, nbx, W, Wbf, n4w, nbw, E, Ebf, Etbf, C, D);
  }

  // 2) scores = x @ E^T   [Mrows, C] fp32   (8-phase 256^2)
  gemm_bt256p_k<0><<<dim3(C / 256, Mrows / 256), 512, 0, stream>>>(
      xbf, Ebf, Mrows, C, D, D, scores, nullptr, nullptr);

  // 3) probs = softmax(scores) -> bf16, packed in-place
  softmax_rows_k<<<Mrows, 256, 0, stream>>>(scores, probs, C);

  // 4) x2 = x + probs @ E   [Mrows, D] bf16  (256x128 2-phase, 256 blocks)
  gemm2_k<<<dim3(D / 128, Mrows / 256), 512, 0, stream>>>(
      probs, Etbf, Mrows, D, C, 2 * C, x2bf, x);

  // 5) out = leakyrelu(x2 @ W^T + b)  [Mrows, C] fp32  (8-phase 256^2)
  gemm_bt256p_k<2><<<dim3(C / 256, Mrows / 256), 512, 0, stream>>>(
      x2bf, Wbf, Mrows, C, D, D, (float*)d_out, nullptr, bias);
}